// Round 1
// baseline (185.484 us; speedup 1.0000x reference)
//
#include <hip/hip_runtime.h>

#define N_DATA   128
#define SEG_LEN  131072
#define NPROD    (SEG_LEN - 1)
#define N_MAT    8
#define N_MATP   8
#define N_PROCP  5
#define RGAS     8.314f

#define NCH      64          // chunks per row
#define CHUNK    2048        // elements per chunk (NCH*CHUNK == SEG_LEN)
#define TPB      256
#define EPT      8           // CHUNK / TPB

// ws layout (floats):
//   [0,      2048)  rowconst: 128 rows x 16 floats
//   [2048,  10240)  chunksum: 128 x 64
//   [10240, 18432)  chunkoff: 128 x 64
#define WS_ROWCONST 0
#define WS_CHUNKSUM 2048
#define WS_CHUNKOFF 10240

__global__ void setup_consts(const float* __restrict__ pc,
                             const float* __restrict__ raw,
                             const float* __restrict__ lb,
                             const float* __restrict__ ub,
                             const float* __restrict__ sc,
                             const int*  __restrict__ mat_idx,
                             float* __restrict__ rowconst) {
  int r = threadIdx.x;
  if (r >= N_DATA) return;
  auto xv = [&](int i) {
    float s = 1.0f / (1.0f + expf(-raw[i]));
    return s * (ub[i] - lb[i]) + lb[i];
  };
  int pb = N_MAT * N_MATP + r * N_PROCP;
  float SigmaC = xv(pb + 0);
  float K0     = xv(pb + 1);
  float alpha1 = xv(pb + 2);
  float L0     = xv(pb + 3);
  float G200   = xv(pb + 4);
  int mb = mat_idx[r] * N_MATP;
  float Sigma0 = xv(mb + 0);
  float BetaD  = xv(mb + 1);
  float Ea     = xv(mb + 2);
  float Mfda   = xv(mb + 3);
  float Di     = xv(mb + 4);
  float A0     = xv(mb + 5);
  float B0     = xv(mb + 6);
  float l0     = xv(mb + 7);
  float R = pc[r * 4 + 0], T = pc[r * 4 + 1], P = pc[r * 4 + 2];
  float D        = Di * expf(-Ea / (RGAS * T));
  float cbd      = BetaD * D;                 // beta = cbd / (R*Lg + 1e-9)
  float base_num = SigmaC - Mfda * P;
  float inv_tau  = 1.0f / (B0 * l0 + 1e-9f);
  float x_min = sc[0], x_max = sc[1], y_min = sc[2], y_max = sc[3];
  float* rc = rowconst + r * 16;
  rc[0] = alpha1; rc[1] = L0;      rc[2] = G200;  rc[3] = Sigma0;
  rc[4] = A0;     rc[5] = inv_tau; rc[6] = cbd;   rc[7] = base_num;
  rc[8] = R;      rc[9] = K0;      rc[10] = x_min; rc[11] = x_max - x_min;
  rc[12] = y_min; rc[13] = 1.0f / (y_max - y_min); rc[14] = 0.f; rc[15] = 0.f;
}

// s(t), algebraically folded to a single reciprocal:
// sigma_ss = (base_num*u*Lg + Sigma0*cbd) / (Lg*(u+cbd)),  u = R*Lg + 1e-9
__device__ __forceinline__ float stress_s(float t,
    float alpha1, float L0, float G200, float Sigma0, float A0,
    float inv_tau, float cbd, float base_num, float R) {
  float Lg  = G200 * __expf(alpha1 * __logf(t * (1.0f / 200.0f) + 0.001f)) + L0;
  float u   = R * Lg + 1e-9f;
  float num = base_num * u * Lg + Sigma0 * cbd;
  float den = Lg * (u + cbd);
  float sigma_ss = num * __builtin_amdgcn_rcpf(den);
  return sigma_ss + A0 * __expf(-t * inv_tau);
}

__global__ __launch_bounds__(TPB) void pass1(const float* __restrict__ x,
                                             const float* __restrict__ rowconst,
                                             float* __restrict__ chunksum) {
  int b   = blockIdx.x;
  int row = b >> 6;
  int ch  = b & (NCH - 1);
  const float* rc = rowconst + row * 16;
  float alpha1 = rc[0], L0 = rc[1], G200 = rc[2], Sigma0 = rc[3], A0 = rc[4];
  float inv_tau = rc[5], cbd = rc[6], base_num = rc[7], R = rc[8];
  float x_min = rc[10], x_sc = rc[11];

  int tid   = threadIdx.x;
  long rowbase = (long)row * SEG_LEN;
  int  gbase   = ch * CHUNK + tid * EPT;   // product index base within row
  const float* xp = x + rowbase + gbase;

  float4 a = *(const float4*)xp;
  float4 bq = *(const float4*)(xp + 4);
  float xn = (gbase + EPT < SEG_LEN) ? xp[EPT] : 0.0f;
  float tv[9];
  tv[0] = a.x * x_sc + x_min;  tv[1] = a.y * x_sc + x_min;
  tv[2] = a.z * x_sc + x_min;  tv[3] = a.w * x_sc + x_min;
  tv[4] = bq.x * x_sc + x_min; tv[5] = bq.y * x_sc + x_min;
  tv[6] = bq.z * x_sc + x_min; tv[7] = bq.w * x_sc + x_min;
  tv[8] = xn * x_sc + x_min;

  float sum = 0.0f;
#pragma unroll
  for (int k = 0; k < EPT; k++) {
    if (gbase + k < NPROD) {
      float s = stress_s(tv[k], alpha1, L0, G200, Sigma0, A0, inv_tau, cbd, base_num, R);
      sum += s * (tv[k + 1] - tv[k]);
    }
  }

  // block reduce (4 waves)
  int lane = tid & 63, wv = tid >> 6;
  float s = sum;
#pragma unroll
  for (int d = 32; d > 0; d >>= 1) s += __shfl_down(s, d);
  __shared__ float ws4[4];
  if (lane == 0) ws4[wv] = s;
  __syncthreads();
  if (tid == 0) chunksum[row * NCH + ch] = ws4[0] + ws4[1] + ws4[2] + ws4[3];
}

__global__ __launch_bounds__(64) void pass2(const float* __restrict__ chunksum,
                                            float* __restrict__ chunkoff) {
  int row  = blockIdx.x;
  int lane = threadIdx.x;
  float v = chunksum[row * NCH + lane];
  float incl = v;
#pragma unroll
  for (int d = 1; d < 64; d <<= 1) {
    float n = __shfl_up(incl, d);
    if (lane >= d) incl += n;
  }
  chunkoff[row * NCH + lane] = incl - v;   // exclusive prefix of chunk sums
}

__global__ __launch_bounds__(TPB) void pass3(const float* __restrict__ x,
                                             const float* __restrict__ rowconst,
                                             const float* __restrict__ chunkoff,
                                             float* __restrict__ out) {
  __shared__ float tile[TPB * 9];  // padded: thread t's 8 values at t*9+k (conflict-free writes)
  __shared__ float wsum[4];

  int b   = blockIdx.x;
  int row = b >> 6;
  int ch  = b & (NCH - 1);
  const float* rc = rowconst + row * 16;
  float alpha1 = rc[0], L0 = rc[1], G200 = rc[2], Sigma0 = rc[3], A0 = rc[4];
  float inv_tau = rc[5], cbd = rc[6], base_num = rc[7], R = rc[8];
  float K0 = rc[9], x_min = rc[10], x_sc = rc[11], y_min = rc[12], inv_yr = rc[13];

  int tid   = threadIdx.x;
  long rowbase = (long)row * SEG_LEN;
  int  gbase   = ch * CHUNK + tid * EPT;
  const float* xp = x + rowbase + gbase;

  float4 a = *(const float4*)xp;
  float4 bq = *(const float4*)(xp + 4);
  float xn = (gbase + EPT < SEG_LEN) ? xp[EPT] : 0.0f;
  float tv[9];
  tv[0] = a.x * x_sc + x_min;  tv[1] = a.y * x_sc + x_min;
  tv[2] = a.z * x_sc + x_min;  tv[3] = a.w * x_sc + x_min;
  tv[4] = bq.x * x_sc + x_min; tv[5] = bq.y * x_sc + x_min;
  tv[6] = bq.z * x_sc + x_min; tv[7] = bq.w * x_sc + x_min;
  tv[8] = xn * x_sc + x_min;

  float pref[EPT];
  float run = 0.0f;
#pragma unroll
  for (int k = 0; k < EPT; k++) {
    float p = 0.0f;
    if (gbase + k < NPROD) {
      float s = stress_s(tv[k], alpha1, L0, G200, Sigma0, A0, inv_tau, cbd, base_num, R);
      p = s * (tv[k + 1] - tv[k]);
    }
    run += p;
    pref[k] = run;  // inclusive within thread
  }

  // wave inclusive scan of thread sums
  int lane = tid & 63, wv = tid >> 6;
  float incl = run;
#pragma unroll
  for (int d = 1; d < 64; d <<= 1) {
    float n = __shfl_up(incl, d);
    if (lane >= d) incl += n;
  }
  if (lane == 63) wsum[wv] = incl;
  __syncthreads();
  float woff = 0.0f;
#pragma unroll
  for (int w = 0; w < 4; w++) woff += (w < wv) ? wsum[w] : 0.0f;
  float excl_thread = incl - run + woff;

  float choff = chunkoff[row * NCH + ch];
  float addv  = K0 + choff + excl_thread;
#pragma unroll
  for (int k = 0; k < EPT; k++)
    tile[tid * 9 + k] = (addv + pref[k] - y_min) * inv_yr;
  __syncthreads();

  // coalesced store: out[rowbase + ch*CHUNK + 1 + j], j = k*TPB + tid
  long obase = rowbase + ch * CHUNK + 1;
#pragma unroll
  for (int k = 0; k < EPT; k++) {
    int j = k * TPB + tid;
    int g = ch * CHUNK + j;
    if (g < NPROD) out[obase + j] = tile[(j >> 3) * 9 + (j & 7)];
  }
  if (ch == 0 && tid == 0) out[rowbase] = (K0 - y_min) * inv_yr;
}

extern "C" void kernel_launch(void* const* d_in, const int* in_sizes, int n_in,
                              void* d_out, int out_size, void* d_ws, size_t ws_size,
                              hipStream_t stream) {
  const float* x_scaled  = (const float*)d_in[0];
  const float* process_c = (const float*)d_in[1];
  const float* raw       = (const float*)d_in[2];
  const float* lb        = (const float*)d_in[3];
  const float* ub        = (const float*)d_in[4];
  const float* sc        = (const float*)d_in[5];
  // d_in[6] = fit_index (unused by the reference computation)
  const int*   mat_idx   = (const int*)d_in[7];
  float* out = (float*)d_out;

  float* wsf      = (float*)d_ws;
  float* rowconst = wsf + WS_ROWCONST;
  float* chunksum = wsf + WS_CHUNKSUM;
  float* chunkoff = wsf + WS_CHUNKOFF;

  setup_consts<<<1, 128, 0, stream>>>(process_c, raw, lb, ub, sc, mat_idx, rowconst);
  pass1<<<N_DATA * NCH, TPB, 0, stream>>>(x_scaled, rowconst, chunksum);
  pass2<<<N_DATA, 64, 0, stream>>>(chunksum, chunkoff);
  pass3<<<N_DATA * NCH, TPB, 0, stream>>>(x_scaled, rowconst, chunkoff, out);
}